// Round 2
// baseline (303560.718 us; speedup 1.0000x reference)
//
#include <hip/hip_runtime.h>
#include <math.h>

#define BATCH 128
#define TDEC  550
#define TENC  500
#define EDIM  512
#define VOC   31
#define NBLK  256
#define NTHR  512

// ---------------- workspace layout (float offsets) ----------------
#define OFF_WA   0u                          // [2048][1024] cols 0..511 = M (s-part), 512..1023 = w_hh0
#define OFF_WB   (OFF_WA + 2097152u)         // [2048][1024] cols 0..511 = w_ih1, 512..1023 = w_hh1
#define OFF_GM   (OFF_WB + 2097152u)         // [512][1024]  cols 0..511 = w_o2c[:, :512], 512.. = M2
#define OFF_E2G  (OFF_GM + 524288u)          // [31][2048]
#define OFF_BA   (OFF_E2G + 63488u)          // [2048]
#define OFF_BB   (OFF_BA + 2048u)            // [2048]
#define OFF_BG   (OFF_BB + 2048u)            // [512]
#define OFF_ST   (OFF_BG + 512u)             // s~ [512][128]
#define OFF_H0T0 (OFF_ST   + 65536u)
#define OFF_H0T1 (OFF_H0T0 + 65536u)
#define OFF_H1T0 (OFF_H0T1 + 65536u)
#define OFF_H1T1 (OFF_H1T0 + 65536u)
#define OFF_C0T  (OFF_H1T1 + 65536u)
#define OFF_C1T  (OFF_C0T  + 65536u)
#define OFF_P    (OFF_C1T  + 65536u)         // exp(e) [128][512] (500 used)
#define OFF_PL   (OFF_P    + 65536u)         // l partials [128][2]
#define OFF_PS   (OFF_PL   + 256u)           // s partials [128][2][512]
#define OFF_LB   (OFF_PS   + 131072u)        // logits dbl-buf [2][128][32]
#define OFF_BAR  (OFF_LB   + 8192u)          // barrier flags/gen
#define OFF_WKT  (OFF_BAR  + 8192u)          // wkT [512 e][512 d]
#define OFF_H1BK (OFF_WKT  + 262144u)        // h1 in [b][k] layout [128][512]

// ---------------- device-coherent accessors (compiler-visible) ----------------
// Relaxed agent-scope atomics: HIP emits device-scope (sc1) loads/stores that
// are served at the MALL (the cross-XCD coherence point) with NO fences and
// full compiler waitcnt/spill tracking.  All cross-block mutable state goes
// through these; read-only data stays in normal cached loads (L2 stays warm
// forever because nothing ever invalidates it).
__device__ __forceinline__ float ldv(const float* p) {
  return __hip_atomic_load((const float*)p, __ATOMIC_RELAXED, __HIP_MEMORY_SCOPE_AGENT);
}
__device__ __forceinline__ void stv(float* p, float v) {
  __hip_atomic_store(p, v, __ATOMIC_RELAXED, __HIP_MEMORY_SCOPE_AGENT);
}

// ---------------- init kernel 1: copies / biases / zeros / wkT ----------------
__global__ void initCopy(const float* __restrict__ w_hh0, const float* __restrict__ w_ih1,
                         const float* __restrict__ w_hh1, const float* __restrict__ w_o2c,
                         const float* __restrict__ b_ih0, const float* __restrict__ b_hh0,
                         const float* __restrict__ b_ih1, const float* __restrict__ b_hh1,
                         const float* __restrict__ b_o2c, const float* __restrict__ wk,
                         float* __restrict__ ws)
{
  const unsigned n0 = 2048u*512u;
  const unsigned n1 = 2048u*512u;
  const unsigned n2 = 2048u*512u;
  const unsigned n3 = 512u*512u;
  const unsigned nz = 7u*65536u;
  const unsigned nw = 262144u;
  const unsigned NT = n0+n1+n2+n3 + 2048u+2048u+512u + nz + 8192u + 8192u + nw;
  for (unsigned i = blockIdx.x*blockDim.x + threadIdx.x; i < NT; i += gridDim.x*blockDim.x) {
    unsigned j = i;
    if (j < n0) { unsigned r = j>>9, k = j&511u;
      ws[OFF_WA + r*1024u + 512u + k] = w_hh0[j]; continue; }
    j -= n0;
    if (j < n1) { unsigned r = j>>9, k = j&511u;
      ws[OFF_WB + r*1024u + k] = w_ih1[j]; continue; }
    j -= n1;
    if (j < n2) { unsigned r = j>>9, k = j&511u;
      ws[OFF_WB + r*1024u + 512u + k] = w_hh1[j]; continue; }
    j -= n2;
    if (j < n3) { unsigned r = j>>9, k = j&511u;
      ws[OFF_GM + r*1024u + k] = w_o2c[r*1024u + k]; continue; }
    j -= n3;
    if (j < 2048u) { ws[OFF_BA + j] = b_ih0[j] + b_hh0[j]; continue; }
    j -= 2048u;
    if (j < 2048u) { ws[OFF_BB + j] = b_ih1[j] + b_hh1[j]; continue; }
    j -= 2048u;
    if (j < 512u)  { ws[OFF_BG + j] = b_o2c[j]; continue; }
    j -= 512u;
    if (j < nz)    { ws[OFF_ST + j] = 0.f; continue; }
    j -= nz;
    if (j < 8192u) {
      unsigned buf = j>>12, v = j & 31u;
      ws[OFF_LB + j] = (buf==1u && v==0u) ? 1e9f : 0.f;   // argmax -> SOS(=0) at t=0
      continue; }
    j -= 8192u;
    if (j < 8192u) { ((unsigned*)(ws + OFF_BAR))[j] = 0u; continue; }
    j -= 8192u;
    { unsigned e = j>>9, d = j&511u;
      ws[OFF_WKT + j] = wk[d*512u + e]; }
  }
}

// ---------------- init kernel 2: folded weight GEMMs ----------------
__global__ void initGemm(const float* __restrict__ w_ih0, const float* __restrict__ w_o2c,
                         const float* __restrict__ wvm, const float* __restrict__ emb,
                         float* __restrict__ ws)
{
  const unsigned n0 = 2048u*512u;
  const unsigned n1 = 512u*512u;
  const unsigned n2 = 31u*2048u;
  const unsigned NT = n0+n1+n2;
  for (unsigned i = blockIdx.x*blockDim.x + threadIdx.x; i < NT; i += gridDim.x*blockDim.x) {
    if (i < n0) {
      unsigned r = i>>9, d = i&511u;
      const float* a = w_ih0 + (size_t)r*1024u + 512u;
      const float* b = wvm + (size_t)d*512u;
      float s = 0.f;
      for (int k = 0; k < 512; ++k) s = fmaf(a[k], b[k], s);
      ws[OFF_WA + r*1024u + d] = s;
    } else if (i < n0+n1) {
      unsigned j = i - n0; unsigned r = j>>9, d = j&511u;
      const float* a = w_o2c + (size_t)r*1024u + 512u;
      const float* b = wvm + (size_t)d*512u;
      float s = 0.f;
      for (int k = 0; k < 512; ++k) s = fmaf(a[k], b[k], s);
      ws[OFF_GM + r*1024u + 512u + d] = s;
    } else {
      unsigned j = i - n0 - n1; unsigned v = j>>11, g = j&2047u;
      const float* a = emb + (size_t)v*512u;
      const float* b = w_ih0 + (size_t)g*1024u;
      float s = 0.f;
      for (int k = 0; k < 512; ++k) s = fmaf(a[k], b[k], s);
      ws[OFF_E2G + v*2048u + g] = s;
    }
  }
}

// ---------------- fence-free flag-array grid barrier ----------------
// All cross-block data moves via device-scope (sc1) ops which are coherent at
// the MALL.  Each wave drains its own vmem (s_waitcnt vmcnt(0)) before
// __syncthreads, so a RELAXED flag store is a valid release: data reaches the
// coherence point before the flag does.  NO agent fences -> no buffer_wbl2 /
// buffer_inv, so per-XCD L2s stay warm with weights/enc for all 550 steps.
__device__ __forceinline__ void gridbar(float* ws, unsigned tgt)
{
  unsigned* base = (unsigned*)(ws + OFF_BAR);
  asm volatile("s_waitcnt vmcnt(0)" ::: "memory");   // own stores at coherence point
  __syncthreads();                                   // whole block's stores drained
  if (blockIdx.x == 0) {
    const int tid = threadIdx.x;
    if (tid > 0 && tid < 256) {
      unsigned* f = base + tid*16;
      while (__hip_atomic_load(f, __ATOMIC_RELAXED, __HIP_MEMORY_SCOPE_AGENT) < tgt)
        __builtin_amdgcn_s_sleep(4);
    }
    __syncthreads();
    if (tid == 0)
      __hip_atomic_store(base + 4096, tgt, __ATOMIC_RELAXED, __HIP_MEMORY_SCOPE_AGENT);
    __syncthreads();
  } else {
    if (threadIdx.x == 0) {
      __hip_atomic_store(base + blockIdx.x*16, tgt, __ATOMIC_RELAXED, __HIP_MEMORY_SCOPE_AGENT);
      while (__hip_atomic_load(base + 4096, __ATOMIC_RELAXED, __HIP_MEMORY_SCOPE_AGENT) < tgt)
        __builtin_amdgcn_s_sleep(8);
    }
    __syncthreads();
  }
}

__device__ __forceinline__ float sigm(float x) { return 1.f/(1.f + expf(-x)); }

// double-buffered device-scope x-read + FMA macro (compiler-visible loads)
#define XLOOP(accv, xbp, wrv) {                                         \
  float xA_[32], xB_[32];                                               \
  _Pragma("unroll")                                                     \
  for (int u_ = 0; u_ < 32; ++u_) xA_[u_] = ldv((xbp) + (size_t)u_*128u); \
  for (int kb_ = 0; kb_ < 256; kb_ += 64) {                             \
    _Pragma("unroll")                                                   \
    for (int u_ = 0; u_ < 32; ++u_)                                     \
      xB_[u_] = ldv((xbp) + (size_t)(kb_+32+u_)*128u);                  \
    _Pragma("unroll")                                                   \
    for (int u_ = 0; u_ < 32; ++u_) {                                   \
      float xv_ = xA_[u_];                                              \
      _Pragma("unroll")                                                 \
      for (int r_ = 0; r_ < 8; ++r_)                                    \
        accv[r_] = fmaf(xv_, wrv[r_][kb_+u_], accv[r_]);                \
    }                                                                   \
    if (kb_ + 64 < 256) {                                               \
      _Pragma("unroll")                                                 \
      for (int u_ = 0; u_ < 32; ++u_)                                   \
        xA_[u_] = ldv((xbp) + (size_t)(kb_+64+u_)*128u);                \
    }                                                                   \
    _Pragma("unroll")                                                   \
    for (int u_ = 0; u_ < 32; ++u_) {                                   \
      float xv_ = xB_[u_];                                              \
      _Pragma("unroll")                                                 \
      for (int r_ = 0; r_ < 8; ++r_)                                    \
        accv[r_] = fmaf(xv_, wrv[r_][kb_+32+u_], accv[r_]);             \
    }                                                                   \
  }                                                                     \
}

// ---------------- main persistent kernel ----------------
__launch_bounds__(NTHR)
__global__ void speller_main(const float* __restrict__ enc, const float* __restrict__ emb,
                             const float* __restrict__ wk,  const float* __restrict__ bcp,
                             float* __restrict__ ws, float* __restrict__ out)
{
  __shared__ __align__(16) float smem[15616];
  __shared__ int symL[128];
  const int tid = threadIdx.x;
  const int blk = blockIdx.x;
  unsigned bstep = 0;

  float* rawout  = out;                                   // [128][550][31]
  float* attnout = out + (size_t)BATCH*TDEC*VOC;          // [128][550][500]

  for (int t = 0; t < TDEC; ++t) {
    const int p = t & 1;
    float*       h0_cur  = ws + (p ? OFF_H0T1 : OFF_H0T0);
    const float* h0_prev = ws + (p ? OFF_H0T0 : OFF_H0T1);
    float*       h1_cur  = ws + (p ? OFF_H1T1 : OFF_H1T0);
    const float* h1_prev = ws + (p ? OFF_H1T0 : OFF_H1T1);

    // ========== Phase A : argmax feedback + LSTM0 (block owns j0=blk*2) ==========
    {
      const float* Lb = ws + OFF_LB + (size_t)(p^1)*4096u;
      if (blk < 16) {
        if (t > 0) {
          for (int i = tid; i < 248; i += NTHR) {
            int bl = i / 31, v = i - bl*31;
            int bb = blk*8 + bl;
            rawout[((size_t)bb*TDEC + (t-1))*VOC + v] = ldv(Lb + bb*32 + v) + bcp[v];
          }
        }
      } else if (blk == 16) {
        float* Lz = ws + OFF_LB + (size_t)p*4096u;
        for (int i = tid; i < 4096; i += NTHR) stv(Lz + i, 0.f);
      }
      if (tid < 128) {
        float lv[VOC];
        #pragma unroll
        for (int v = 0; v < VOC; ++v) lv[v] = ldv(Lb + tid*32 + v);
        float best = -3.4e38f; int sy = 0;
        #pragma unroll
        for (int v = 0; v < VOC; ++v) {
          float f = lv[v] + bcp[v];
          if (f > best) { best = f; sy = v; }
        }
        symL[tid] = sy;
      }
      const int b  = tid & 127;
      const int kg = tid >> 7;
      const int j0 = blk*2;
      const float* xb = ((kg < 2) ? (ws + OFF_ST + (size_t)kg*256u*128u)
                                  : (h0_prev + (size_t)(kg-2)*256u*128u)) + b;
      const float* wr[8];
      #pragma unroll
      for (int r = 0; r < 8; ++r) {
        int gi = r >> 1, jl = r & 1;
        wr[r] = ws + OFF_WA + (size_t)(gi*512 + j0 + jl)*1024u + kg*256;
      }
      float acc[8] = {0,0,0,0,0,0,0,0};
      XLOOP(acc, xb, wr);
      float* lacc = smem;
      __syncthreads();
      #pragma unroll
      for (int r = 0; r < 8; ++r) lacc[(kg*128 + b)*9 + r] = acc[r];
      __syncthreads();
      if (tid < 256) {
        const int bb = tid & 127, jl = tid >> 7;
        const int j = j0 + jl;
        float gv[4];
        #pragma unroll
        for (int gi = 0; gi < 4; ++gi) {
          float s = 0.f;
          #pragma unroll
          for (int kg2 = 0; kg2 < 4; ++kg2) s += lacc[(kg2*128 + bb)*9 + gi*2 + jl];
          s += (ws + OFF_E2G)[(size_t)symL[bb]*2048u + gi*512 + j];
          s += (ws + OFF_BA)[gi*512 + j];
          gv[gi] = s;
        }
        float ig = sigm(gv[0]), fg = sigm(gv[1]);
        float gg = tanhf(gv[2]), og = sigm(gv[3]);
        float cold = (ws + OFF_C0T)[(size_t)j*128 + bb];    // block-private: normal cached
        float cnew = fg*cold + ig*gg;
        (ws + OFF_C0T)[(size_t)j*128 + bb] = cnew;
        stv(&h0_cur[(size_t)j*128 + bb], og*tanhf(cnew));
      }
    }
    gridbar(ws, ++bstep);

    // ========== Phase B : LSTM1 (also writes h1bk transposed copy) ==========
    {
      const int b  = tid & 127;
      const int kg = tid >> 7;
      const int j0 = blk*2;
      const float* xb = ((kg < 2) ? (h0_cur + (size_t)kg*256u*128u)
                                  : (h1_prev + (size_t)(kg-2)*256u*128u)) + b;
      const float* wr[8];
      #pragma unroll
      for (int r = 0; r < 8; ++r) {
        int gi = r >> 1, jl = r & 1;
        wr[r] = ws + OFF_WB + (size_t)(gi*512 + j0 + jl)*1024u + kg*256;
      }
      float acc[8] = {0,0,0,0,0,0,0,0};
      XLOOP(acc, xb, wr);
      float* lacc = smem;
      __syncthreads();
      #pragma unroll
      for (int r = 0; r < 8; ++r) lacc[(kg*128 + b)*9 + r] = acc[r];
      __syncthreads();
      if (tid < 256) {
        const int bb = tid & 127, jl = tid >> 7;
        const int j = j0 + jl;
        float gv[4];
        #pragma unroll
        for (int gi = 0; gi < 4; ++gi) {
          float s = 0.f;
          #pragma unroll
          for (int kg2 = 0; kg2 < 4; ++kg2) s += lacc[(kg2*128 + bb)*9 + gi*2 + jl];
          s += (ws + OFF_BB)[gi*512 + j];
          gv[gi] = s;
        }
        float ig = sigm(gv[0]), fg = sigm(gv[1]);
        float gg = tanhf(gv[2]), og = sigm(gv[3]);
        float cold = (ws + OFF_C1T)[(size_t)j*128 + bb];
        float cnew = fg*cold + ig*gg;
        (ws + OFF_C1T)[(size_t)j*128 + bb] = cnew;
        float hval = og*tanhf(cnew);
        stv(&h1_cur[(size_t)j*128 + bb], hval);
        stv(ws + OFF_H1BK + (size_t)bb*512u + j, hval);
      }
    }
    gridbar(ws, ++bstep);

    // ========== Phase C : q + pipelined attention (block=(b,tau)) ==========
    {
      const int b = blk >> 1, tau = blk & 1;
      const int tbase = tau*250;
      float* tile = smem;            // [25][520] = 13000
      float* qL   = smem + 13000;    // 512
      float* pL   = smem + 13520;    // 32
      float* sred = smem + 13568;    // [4][512]
      float* h1L  = sred;            // alias (used before sred)

      if (tid < 128) {
        const float* hp = ws + OFF_H1BK + (size_t)b*512u + tid*4;
        float h0v = ldv(hp+0), h1v = ldv(hp+1), h2v = ldv(hp+2), h3v = ldv(hp+3);
        h1L[tid*4+0] = h0v; h1L[tid*4+1] = h1v;
        h1L[tid*4+2] = h2v; h1L[tid*4+3] = h3v;
      }
      __syncthreads();
      // q[d] = sum_e wkT[e][d]*h1[e], 4-way e-split (wkT read-only, L2-warm)
      {
        const int eg = tid >> 7, dqq = (tid & 127)*4;
        const int e0 = eg*128;
        float4 qa = {0.f,0.f,0.f,0.f};
        const float* wkt = ws + OFF_WKT;
        for (int e = 0; e < 128; ++e) {
          float hv = h1L[e0 + e];
          float4 wv4 = *(const float4*)(wkt + (size_t)(e0+e)*512u + dqq);
          qa.x = fmaf(hv, wv4.x, qa.x); qa.y = fmaf(hv, wv4.y, qa.y);
          qa.z = fmaf(hv, wv4.z, qa.z); qa.w = fmaf(hv, wv4.w, qa.w);
        }
        *(float4*)(tile + eg*512 + dqq) = qa;   // tile as scratch
      }
      __syncthreads();
      if (tid < 128) {
        int dqq = tid*4;
        float4 a0 = *(float4*)(tile + dqq);
        float4 a1 = *(float4*)(tile + 512 + dqq);
        float4 a2 = *(float4*)(tile + 1024 + dqq);
        float4 a3 = *(float4*)(tile + 1536 + dqq);
        float4 q4;
        q4.x = a0.x+a1.x+a2.x+a3.x; q4.y = a0.y+a1.y+a2.y+a3.y;
        q4.z = a0.z+a1.z+a2.z+a3.z; q4.w = a0.w+a1.w+a2.w+a3.w;
        *(float4*)(qL + dqq) = q4;
      }
      // prologue: prefetch tile 0 (enc: read-only, normal cached loads)
      float4 rv[7];
      const float* encb = enc + ((size_t)b*TENC + tbase)*EDIM;
      #pragma unroll
      for (int jj = 0; jj < 7; ++jj) {
        int i2 = tid + jj*512;
        if (i2 < 3200) rv[jj] = *(const float4*)(encb + (size_t)i2*4u);
      }
      float sa0=0.f, sa1=0.f, sa2=0.f, sa3=0.f;
      float ltot = 0.f;
      const int rr = tid >> 3, cc = tid & 7;
      const int qr = tid >> 7, dqq = (tid & 127)*4;
      const int rs = qr*6 + (qr>0 ? 1 : 0);
      const int rcnt = (qr==0) ? 7 : 6;
      __syncthreads();   // qL ready, tile scratch free
      for (int ti = 0; ti < 10; ++ti) {
        #pragma unroll
        for (int jj = 0; jj < 7; ++jj) {
          int i2 = tid + jj*512;
          if (i2 < 3200) { int r = i2 >> 7, c = i2 & 127; *(float4*)(tile + r*520 + c*4) = rv[jj]; }
        }
        __syncthreads();
        if (ti < 9) {      // prefetch next tile (overlaps compute)
          const float* encn = encb + (size_t)(ti+1)*25u*EDIM;
          #pragma unroll
          for (int jj = 0; jj < 7; ++jj) {
            int i2 = tid + jj*512;
            if (i2 < 3200) rv[jj] = *(const float4*)(encn + (size_t)i2*4u);
          }
        }
        if (rr < 25) {
          float a = 0.f;
          const float* tr = tile + rr*520;
          #pragma unroll
          for (int i = 0; i < 16; ++i) {
            int d = i*32 + cc*4;
            float4 tv = *(const float4*)(tr + d);
            float4 qv = *(const float4*)(qL + d);
            a = fmaf(tv.x,qv.x,a); a = fmaf(tv.y,qv.y,a);
            a = fmaf(tv.z,qv.z,a); a = fmaf(tv.w,qv.w,a);
          }
          a += __shfl_xor(a, 1); a += __shfl_xor(a, 2); a += __shfl_xor(a, 4);
          if (cc == 0) {
            float pv = expf(a);
            pL[rr] = pv;
            stv(ws + OFF_P + (size_t)b*512u + tbase + ti*25 + rr, pv);
          }
        }
        __syncthreads();
        if (tid < 32) {
          float pv = (tid < 25) ? pL[tid] : 0.f;
          pv += __shfl_xor(pv, 1); pv += __shfl_xor(pv, 2); pv += __shfl_xor(pv, 4);
          pv += __shfl_xor(pv, 8); pv += __shfl_xor(pv, 16);
          if (tid == 0) ltot += pv;
        }
        {
          const float* tb = tile + dqq;
          for (int r = rs; r < rs + rcnt; ++r) {
            float w = pL[r];
            float4 tv = *(const float4*)(tb + r*520);
            sa0 = fmaf(w, tv.x, sa0); sa1 = fmaf(w, tv.y, sa1);
            sa2 = fmaf(w, tv.z, sa2); sa3 = fmaf(w, tv.w, sa3);
          }
        }
        __syncthreads();
      }
      {
        float4 sv; sv.x = sa0; sv.y = sa1; sv.z = sa2; sv.w = sa3;
        *(float4*)(sred + qr*512 + dqq) = sv;
      }
      __syncthreads();
      if (tid < 128) {
        int d4 = tid*4;
        float4 s0 = *(float4*)(sred + d4);
        float4 s1 = *(float4*)(sred + 512 + d4);
        float4 s2 = *(float4*)(sred + 1024 + d4);
        float4 s3 = *(float4*)(sred + 1536 + d4);
        float* pd = ws + OFF_PS + (size_t)(b*2 + tau)*512u + d4;
        stv(pd+0, s0.x+s1.x+s2.x+s3.x);
        stv(pd+1, s0.y+s1.y+s2.y+s3.y);
        stv(pd+2, s0.z+s1.z+s2.z+s3.z);
        stv(pd+3, s0.w+s1.w+s2.w+s3.w);
      }
      if (tid == 0) stv(ws + OFF_PL + b*2 + tau, ltot);
    }
    gridbar(ws, ++bstep);

    // ========== Phase D : ctx combine + o2c + logits + outputs ==========
    {
      const int bt = blk >> 4, it = blk & 15;
      const int b0 = bt*8, i0 = it*32;
      float* xo   = smem;            // [8][1032]
      float* scsL = smem + 8256;     // 8
      float* hidP = smem + 8264;     // [2][256]
      float* hidL = smem + 8776;     // [8][33]
      if (tid < 8) {
        int bb = b0 + tid;
        float l0 = ldv(ws + OFF_PL + bb*2);
        float l1 = ldv(ws + OFF_PL + bb*2 + 1);
        scsL[tid] = 1.f / (l0 + l1);
      }
      __syncthreads();
      for (int i = tid; i < 1024; i += NTHR) {
        int bl = i >> 7, kq = (i & 127)*4;
        const float* hp = ws + OFF_H1BK + (size_t)(b0+bl)*512u + kq;
        float h0v = ldv(hp+0), h1v = ldv(hp+1), h2v = ldv(hp+2), h3v = ldv(hp+3);
        xo[bl*1032 + kq+0] = h0v; xo[bl*1032 + kq+1] = h1v;
        xo[bl*1032 + kq+2] = h2v; xo[bl*1032 + kq+3] = h3v;
      }
      for (int i = tid; i < 1024; i += NTHR) {
        int bl = i >> 7, dq2 = (i & 127)*4;
        const float* psd = ws + OFF_PS + (size_t)(b0 + bl)*2u*512u;
        float a0 = ldv(psd + dq2+0), a1 = ldv(psd + dq2+1);
        float a2 = ldv(psd + dq2+2), a3 = ldv(psd + dq2+3);
        float b0v = ldv(psd + 512 + dq2+0), b1v = ldv(psd + 512 + dq2+1);
        float b2v = ldv(psd + 512 + dq2+2), b3v = ldv(psd + 512 + dq2+3);
        float sc = scsL[bl];
        xo[bl*1032 + 512 + dq2+0] = (a0+b0v)*sc;
        xo[bl*1032 + 512 + dq2+1] = (a1+b1v)*sc;
        xo[bl*1032 + 512 + dq2+2] = (a2+b2v)*sc;
        xo[bl*1032 + 512 + dq2+3] = (a3+b3v)*sc;
      }
      __syncthreads();
      {
        const int bl = tid & 7, il = (tid >> 3) & 31, kh = tid >> 8;
        float a = 0.f;
        const float4* Gr = (const float4*)(ws + OFF_GM + (size_t)(i0 + il)*1024u + kh*512);
        const float4* xr = (const float4*)(xo + bl*1032 + kh*512);
        for (int k2 = 0; k2 < 128; ++k2) {
          float4 g = Gr[k2], x = xr[k2];
          a = fmaf(g.x,x.x,a); a = fmaf(g.y,x.y,a);
          a = fmaf(g.z,x.z,a); a = fmaf(g.w,x.w,a);
        }
        hidP[(kh << 8) + (tid & 255)] = a;
      }
      __syncthreads();
      if (tid < 256) {
        int bl = tid & 7, il = tid >> 3;
        float h = hidP[tid] + hidP[256 + tid] + (ws + OFF_BG)[i0 + il];
        hidL[bl*33 + il] = fmaxf(h, 0.f);
      }
      if (it == 0) {
        for (int i = tid; i < 1000; i += NTHR) {
          int bl = i / 125, f = i - bl*125;
          int bb = b0 + bl;
          const float* pp = ws + OFF_P + (size_t)bb*512u + f*4;
          float p0v = ldv(pp+0), p1v = ldv(pp+1), p2v = ldv(pp+2), p3v = ldv(pp+3);
          float sc = scsL[bl];
          float4 v; v.x = p0v*sc; v.y = p1v*sc; v.z = p2v*sc; v.w = p3v*sc;
          *(float4*)(attnout + ((size_t)bb*TDEC + t)*TENC + f*4) = v;
        }
        for (int i = tid; i < 4096; i += NTHR) {
          int bl = i & 7, d = i >> 3;
          stv(ws + OFF_ST + (size_t)d*128 + b0 + bl, xo[bl*1032 + 512 + d]);
        }
      }
      __syncthreads();
      if (tid < 248) {
        int bl = tid & 7, v = tid >> 3;
        float s = 0.f;
        const float* er = emb + (size_t)v*512u + i0;
        const float* hrow = hidL + bl*33;
        #pragma unroll
        for (int ii = 0; ii < 32; ++ii) s = fmaf(hrow[ii], er[ii], s);
        float* Lw = ws + OFF_LB + (size_t)p*4096u;
        atomicAdd(&Lw[(b0 + bl)*32 + v], s);   // device-scope atomic (MALL-coherent)
      }
    }
    gridbar(ws, ++bstep);
  } // t loop

  // final logits row (t = 549, parity 1)
  if (blk < 16) {
    const float* Lb = ws + OFF_LB + 4096u;
    for (int i = tid; i < 248; i += NTHR) {
      int bl = i / 31, v = i - bl*31;
      int bb = blk*8 + bl;
      rawout[((size_t)bb*TDEC + (TDEC-1))*VOC + v] = ldv(Lb + bb*32 + v) + bcp[v];
    }
  }
}

// ---------------- launch ----------------
extern "C" void kernel_launch(void* const* d_in, const int* in_sizes, int n_in,
                              void* d_out, int out_size, void* d_ws, size_t ws_size,
                              hipStream_t stream)
{
  (void)in_sizes; (void)n_in; (void)out_size; (void)ws_size;
  const float* enc   = (const float*)d_in[0];
  const float* emb   = (const float*)d_in[1];
  const float* w_ih0 = (const float*)d_in[2];
  const float* w_hh0 = (const float*)d_in[3];
  const float* b_ih0 = (const float*)d_in[4];
  const float* b_hh0 = (const float*)d_in[5];
  const float* w_ih1 = (const float*)d_in[6];
  const float* w_hh1 = (const float*)d_in[7];
  const float* b_ih1 = (const float*)d_in[8];
  const float* b_hh1 = (const float*)d_in[9];
  const float* wk    = (const float*)d_in[10];
  const float* wvm   = (const float*)d_in[11];
  const float* w_o2c = (const float*)d_in[12];
  const float* b_o2c = (const float*)d_in[13];
  const float* bcp   = (const float*)d_in[14];
  float* ws   = (float*)d_ws;
  float* outp = (float*)d_out;

  initCopy<<<2048, 256, 0, stream>>>(w_hh0, w_ih1, w_hh1, w_o2c,
                                     b_ih0, b_hh0, b_ih1, b_hh1, b_o2c, wk, ws);
  initGemm<<<2048, 256, 0, stream>>>(w_ih0, w_o2c, wvm, emb, ws);
  speller_main<<<NBLK, NTHR, 0, stream>>>(enc, emb, wk, bcp, ws, outp);
}

// Round 3
// 78595.844 us; speedup vs baseline: 3.8623x; 3.8623x over previous
//
#include <hip/hip_runtime.h>
#include <math.h>

#define BATCH 128
#define TDEC  550
#define TENC  500
#define EDIM  512
#define VOC   31
#define NBLK  256
#define NTHR  512

// ---------------- workspace layout (float offsets) ----------------
// WA/WB are now TRANSPOSED (k-major): WAT[k][j] with k in [0,1024), j in [0,2048)
#define OFF_WA   0u                          // WAT [1024][2048]: k<512 = M (s-part), k>=512 = w_hh0
#define OFF_WB   (OFF_WA + 2097152u)         // WBT [1024][2048]: k<512 = w_ih1,      k>=512 = w_hh1
#define OFF_GM   (OFF_WB + 2097152u)         // [512][1024]  cols 0..511 = w_o2c[:, :512], 512.. = M2
#define OFF_E2G  (OFF_GM + 524288u)          // [31][2048]
#define OFF_BA   (OFF_E2G + 63488u)          // [2048]
#define OFF_BB   (OFF_BA + 2048u)            // [2048]
#define OFF_BG   (OFF_BB + 2048u)            // [512]
#define OFF_ST   (OFF_BG + 512u)             // s~ [512][128]
#define OFF_H0T0 (OFF_ST   + 65536u)
#define OFF_H0T1 (OFF_H0T0 + 65536u)
#define OFF_H1T0 (OFF_H0T1 + 65536u)
#define OFF_H1T1 (OFF_H1T0 + 65536u)
#define OFF_C0T  (OFF_H1T1 + 65536u)
#define OFF_C1T  (OFF_C0T  + 65536u)
#define OFF_P    (OFF_C1T  + 65536u)         // exp(e) [128][512] (500 used)
#define OFF_PL   (OFF_P    + 65536u)         // l partials [128][2]
#define OFF_PS   (OFF_PL   + 256u)           // s partials [128][2][512]
#define OFF_LB   (OFF_PS   + 131072u)        // logits dbl-buf [2][128][32]
#define OFF_BAR  (OFF_LB   + 8192u)          // barrier flags/gen
#define OFF_WKT  (OFF_BAR  + 8192u)          // wkT [512 e][512 d]
#define OFF_H1BK (OFF_WKT  + 262144u)        // h1 in [b][k] layout [128][512]

typedef float f32x4_t __attribute__((ext_vector_type(4)));

// ---------------- device-coherent accessors (compiler-visible) ----------------
// Relaxed agent-scope atomics -> device-scope (sc1) dword ops at the MALL
// coherence point.  Only small mutable cross-block state uses these.
__device__ __forceinline__ float ldv(const float* p) {
  return __hip_atomic_load((const float*)p, __ATOMIC_RELAXED, __HIP_MEMORY_SCOPE_AGENT);
}
__device__ __forceinline__ void stv(float* p, float v) {
  __hip_atomic_store(p, v, __ATOMIC_RELAXED, __HIP_MEMORY_SCOPE_AGENT);
}
// nontemporal float4 load: streams without polluting L2 (protects resident weights)
__device__ __forceinline__ float4 ld_nt4(const float* p) {
  f32x4_t v = __builtin_nontemporal_load((const f32x4_t*)p);
  float4 r; r.x = v.x; r.y = v.y; r.z = v.z; r.w = v.w; return r;
}

// ---------------- init kernel 1: copies / biases / zeros / wkT ----------------
__global__ void initCopy(const float* __restrict__ w_hh0, const float* __restrict__ w_ih1,
                         const float* __restrict__ w_hh1, const float* __restrict__ w_o2c,
                         const float* __restrict__ b_ih0, const float* __restrict__ b_hh0,
                         const float* __restrict__ b_ih1, const float* __restrict__ b_hh1,
                         const float* __restrict__ b_o2c, const float* __restrict__ wk,
                         float* __restrict__ ws)
{
  const unsigned n0 = 2048u*512u;      // WAT upper (w_hh0), transposed
  const unsigned n1 = 2048u*512u;      // WBT lower (w_ih1), transposed
  const unsigned n2 = 2048u*512u;      // WBT upper (w_hh1), transposed
  const unsigned n3 = 512u*512u;       // GM left
  const unsigned nz = 7u*65536u;       // ST,H0T0,H0T1,H1T0,H1T1,C0T,C1T
  const unsigned nw = 262144u;         // wkT
  const unsigned NT = n0+n1+n2+n3 + 2048u+2048u+512u + nz + 8192u + 8192u + nw;
  for (unsigned i = blockIdx.x*blockDim.x + threadIdx.x; i < NT; i += gridDim.x*blockDim.x) {
    unsigned j = i;
    if (j < n0) { unsigned r = j & 2047u, k = j >> 11;
      ws[OFF_WA + (512u + k)*2048u + r] = w_hh0[(size_t)r*512u + k]; continue; }
    j -= n0;
    if (j < n1) { unsigned r = j & 2047u, k = j >> 11;
      ws[OFF_WB + k*2048u + r] = w_ih1[(size_t)r*512u + k]; continue; }
    j -= n1;
    if (j < n2) { unsigned r = j & 2047u, k = j >> 11;
      ws[OFF_WB + (512u + k)*2048u + r] = w_hh1[(size_t)r*512u + k]; continue; }
    j -= n2;
    if (j < n3) { unsigned r = j>>9, k = j&511u;
      ws[OFF_GM + r*1024u + k] = w_o2c[r*1024u + k]; continue; }
    j -= n3;
    if (j < 2048u) { ws[OFF_BA + j] = b_ih0[j] + b_hh0[j]; continue; }
    j -= 2048u;
    if (j < 2048u) { ws[OFF_BB + j] = b_ih1[j] + b_hh1[j]; continue; }
    j -= 2048u;
    if (j < 512u)  { ws[OFF_BG + j] = b_o2c[j]; continue; }
    j -= 512u;
    if (j < nz)    { ws[OFF_ST + j] = 0.f; continue; }
    j -= nz;
    if (j < 8192u) {
      unsigned buf = j>>12, v = j & 31u;
      ws[OFF_LB + j] = (buf==1u && v==0u) ? 1e9f : 0.f;   // argmax -> SOS(=0) at t=0
      continue; }
    j -= 8192u;
    if (j < 8192u) { ((unsigned*)(ws + OFF_BAR))[j] = 0u; continue; }
    j -= 8192u;
    { unsigned e = j>>9, d = j&511u;
      ws[OFF_WKT + j] = wk[d*512u + e]; }
  }
}

// ---------------- init kernel 2: folded weight GEMMs ----------------
__global__ void initGemm(const float* __restrict__ w_ih0, const float* __restrict__ w_o2c,
                         const float* __restrict__ wvm, const float* __restrict__ emb,
                         float* __restrict__ ws)
{
  const unsigned n0 = 2048u*512u;   // M  -> WAT lower half (transposed)
  const unsigned n1 = 512u*512u;    // M2 -> GM right
  const unsigned n2 = 31u*2048u;    // E2G
  const unsigned NT = n0+n1+n2;
  for (unsigned i = blockIdx.x*blockDim.x + threadIdx.x; i < NT; i += gridDim.x*blockDim.x) {
    if (i < n0) {
      unsigned r = i & 2047u, d = i >> 11;
      const float* a = w_ih0 + (size_t)r*1024u + 512u;
      const float* b = wvm + (size_t)d*512u;
      float s = 0.f;
      for (int k = 0; k < 512; ++k) s = fmaf(a[k], b[k], s);
      ws[OFF_WA + d*2048u + r] = s;
    } else if (i < n0+n1) {
      unsigned j = i - n0; unsigned r = j>>9, d = j&511u;
      const float* a = w_o2c + (size_t)r*1024u + 512u;
      const float* b = wvm + (size_t)d*512u;
      float s = 0.f;
      for (int k = 0; k < 512; ++k) s = fmaf(a[k], b[k], s);
      ws[OFF_GM + r*1024u + 512u + d] = s;
    } else {
      unsigned j = i - n0 - n1; unsigned v = j>>11, g = j&2047u;
      const float* a = emb + (size_t)v*512u;
      const float* b = w_ih0 + (size_t)g*1024u;
      float s = 0.f;
      for (int k = 0; k < 512; ++k) s = fmaf(a[k], b[k], s);
      ws[OFF_E2G + v*2048u + g] = s;
    }
  }
}

// ---------------- fence-free flag-array grid barrier (proven round 2) ----------
__device__ __forceinline__ void gridbar(float* ws, unsigned tgt)
{
  unsigned* base = (unsigned*)(ws + OFF_BAR);
  asm volatile("s_waitcnt vmcnt(0)" ::: "memory");   // own sc1 stores at coherence point
  __syncthreads();
  if (blockIdx.x == 0) {
    const int tid = threadIdx.x;
    if (tid > 0 && tid < 256) {
      unsigned* f = base + tid*16;
      while (__hip_atomic_load(f, __ATOMIC_RELAXED, __HIP_MEMORY_SCOPE_AGENT) < tgt)
        __builtin_amdgcn_s_sleep(4);
    }
    __syncthreads();
    if (tid == 0)
      __hip_atomic_store(base + 4096, tgt, __ATOMIC_RELAXED, __HIP_MEMORY_SCOPE_AGENT);
    __syncthreads();
  } else {
    if (threadIdx.x == 0) {
      __hip_atomic_store(base + blockIdx.x*16, tgt, __ATOMIC_RELAXED, __HIP_MEMORY_SCOPE_AGENT);
      while (__hip_atomic_load(base + 4096, __ATOMIC_RELAXED, __HIP_MEMORY_SCOPE_AGENT) < tgt)
        __builtin_amdgcn_s_sleep(8);
    }
    __syncthreads();
  }
}

__device__ __forceinline__ float sigm(float x) { return 1.f/(1.f + expf(-x)); }

// ---------------- main persistent kernel ----------------
__launch_bounds__(NTHR)
__global__ void speller_main(const float* __restrict__ enc, const float* __restrict__ emb,
                             const float* __restrict__ wk,  const float* __restrict__ bcp,
                             float* __restrict__ ws, float* __restrict__ out)
{
  __shared__ __align__(16) float smem[15616];
  __shared__ unsigned long long amx[16];
  const int tid = threadIdx.x;
  const int blk = blockIdx.x;
  unsigned bstep = 0;

  float* rawout  = out;                                   // [128][550][31]
  float* attnout = out + (size_t)BATCH*TDEC*VOC;          // [128][550][500]

  // LSTM tiling: 32 hidden-rowgroups x 8 batchgroups, XCD-affine rowgroups
  const int r5  = blk & 31;
  const int hrg = (r5 & 7)*4 + (r5 >> 3);   // blk%8 == hrg>>2 -> XCD-contiguous j-cols
  const int bg  = blk >> 5;
  const int bb0 = bg * 16;

  for (int t = 0; t < TDEC; ++t) {
    const int p = t & 1;
    float*       h0_cur  = ws + (p ? OFF_H0T1 : OFF_H0T0);
    const float* h0_prev = ws + (p ? OFF_H0T0 : OFF_H0T1);
    float*       h1_cur  = ws + (p ? OFF_H1T1 : OFF_H1T0);
    const float* h1_prev = ws + (p ? OFF_H1T0 : OFF_H1T1);

    // ========== Phase A : argmax feedback + LSTM0 ==========
    {
      const float* Lb = ws + OFF_LB + (size_t)(p^1)*4096u;
      if (tid < 16) amx[tid] = 0ull;
      __syncthreads();
      // roles: rawout trickle (hrg==0), LB[p] zeroing (hrg==1)
      if (hrg == 0 && t > 0 && tid < 496) {
        int bl = tid / 31, v = tid - bl*31;
        int bb = bb0 + bl;
        rawout[((size_t)bb*TDEC + (t-1))*VOC + v] = ldv(Lb + bb*32 + v) + bcp[v];
      }
      if (hrg == 1) {
        float* Lz = ws + OFF_LB + (size_t)p*4096u + (size_t)bb0*32u;
        if (tid < 512) stv(Lz + tid, 0.f);
      }
      // parallel argmax for this block's 16 batches (exact first-max semantics)
      if (tid < 496) {
        int bl = tid / 31, v = tid - bl*31;
        float f = ldv(Lb + (size_t)(bb0 + bl)*32u + v) + bcp[v];
        unsigned ub = __float_as_uint(f);
        ub = (ub & 0x80000000u) ? ~ub : (ub | 0x80000000u);
        unsigned long long key = ((unsigned long long)ub << 32) | (unsigned)(31 - v);
        atomicMax(&amx[bl], key);
      }
      // LSTM0 gates: thread (gr,kh): gr=gate-row (4 gates x 16 hidden), kh=k-split
      const int gr = tid & 63, kh = tid >> 6;
      const int gi = gr >> 4, hp = gr & 15;
      const int j  = gi*512 + hrg*16 + hp;
      const float* wcol = ws + OFF_WA + j;
      float acc[16];
      #pragma unroll
      for (int b = 0; b < 16; ++b) acc[b] = 0.f;
      float* xs = smem;                       // [512][16] staged x-slice
      #pragma unroll 1
      for (int pass = 0; pass < 2; ++pass) {
        const float* src = pass ? h0_prev : (ws + OFF_ST);
        __syncthreads();                      // previous contents consumed
        float tmp[16];
        #pragma unroll
        for (int u = 0; u < 16; ++u) {
          int i = tid + u*512;
          tmp[u] = ldv(src + (size_t)(i >> 4)*128u + bb0 + (i & 15));
        }
        #pragma unroll
        for (int u = 0; u < 16; ++u) xs[tid + u*512] = tmp[u];
        __syncthreads();
        const int kb = kh * 64;
        #pragma unroll 8
        for (int kk = 0; kk < 64; ++kk) {
          float w = wcol[(size_t)(pass*512 + kb + kk)*2048u];
          const float* xr = xs + (size_t)(kb + kk)*16u;
          float4 x0 = *(const float4*)(xr);
          float4 x1 = *(const float4*)(xr + 4);
          float4 x2 = *(const float4*)(xr + 8);
          float4 x3 = *(const float4*)(xr + 12);
          acc[0]=fmaf(w,x0.x,acc[0]);  acc[1]=fmaf(w,x0.y,acc[1]);
          acc[2]=fmaf(w,x0.z,acc[2]);  acc[3]=fmaf(w,x0.w,acc[3]);
          acc[4]=fmaf(w,x1.x,acc[4]);  acc[5]=fmaf(w,x1.y,acc[5]);
          acc[6]=fmaf(w,x1.z,acc[6]);  acc[7]=fmaf(w,x1.w,acc[7]);
          acc[8]=fmaf(w,x2.x,acc[8]);  acc[9]=fmaf(w,x2.y,acc[9]);
          acc[10]=fmaf(w,x2.z,acc[10]); acc[11]=fmaf(w,x2.w,acc[11]);
          acc[12]=fmaf(w,x3.x,acc[12]); acc[13]=fmaf(w,x3.y,acc[13]);
          acc[14]=fmaf(w,x3.z,acc[14]); acc[15]=fmaf(w,x3.w,acc[15]);
        }
      }
      __syncthreads();
      float* part = smem;                     // overlays xs: [64 gr][8 kh][17 pad]
      {
        float* pw = part + (size_t)gr*136u + kh*17;
        #pragma unroll
        for (int b = 0; b < 16; ++b) pw[b] = acc[b];
      }
      __syncthreads();
      if (tid < 256) {
        const int hp2 = tid >> 4, b2 = tid & 15;
        const int bb = bb0 + b2;
        const int j512 = hrg*16 + hp2;
        const int sy = 31 - (int)(amx[b2] & 31ull);
        float gv[4];
        #pragma unroll
        for (int g2 = 0; g2 < 4; ++g2) {
          const float* pr = part + (size_t)(g2*16 + hp2)*136u + b2;
          float s = 0.f;
          #pragma unroll
          for (int k2 = 0; k2 < 8; ++k2) s += pr[k2*17];
          s += (ws + OFF_E2G)[(size_t)sy*2048u + g2*512 + j512];
          s += (ws + OFF_BA)[g2*512 + j512];
          gv[g2] = s;
        }
        float ig = sigm(gv[0]), fg = sigm(gv[1]);
        float gg = tanhf(gv[2]), og = sigm(gv[3]);
        float* c0 = ws + OFF_C0T + (size_t)j512*128u + bb;   // block-private: cached
        float cold = *c0;
        float cnew = fg*cold + ig*gg;
        *c0 = cnew;
        stv(h0_cur + (size_t)j512*128u + bb, og*tanhf(cnew));
      }
    }
    gridbar(ws, ++bstep);

    // ========== Phase B : LSTM1 (+ H1BK transposed copy) ==========
    {
      const int gr = tid & 63, kh = tid >> 6;
      const int gi = gr >> 4, hp = gr & 15;
      const int j  = gi*512 + hrg*16 + hp;
      const float* wcol = ws + OFF_WB + j;
      float acc[16];
      #pragma unroll
      for (int b = 0; b < 16; ++b) acc[b] = 0.f;
      float* xs = smem;
      #pragma unroll 1
      for (int pass = 0; pass < 2; ++pass) {
        const float* src = pass ? h1_prev : h0_cur;
        __syncthreads();
        float tmp[16];
        #pragma unroll
        for (int u = 0; u < 16; ++u) {
          int i = tid + u*512;
          tmp[u] = ldv(src + (size_t)(i >> 4)*128u + bb0 + (i & 15));
        }
        #pragma unroll
        for (int u = 0; u < 16; ++u) xs[tid + u*512] = tmp[u];
        __syncthreads();
        const int kb = kh * 64;
        #pragma unroll 8
        for (int kk = 0; kk < 64; ++kk) {
          float w = wcol[(size_t)(pass*512 + kb + kk)*2048u];
          const float* xr = xs + (size_t)(kb + kk)*16u;
          float4 x0 = *(const float4*)(xr);
          float4 x1 = *(const float4*)(xr + 4);
          float4 x2 = *(const float4*)(xr + 8);
          float4 x3 = *(const float4*)(xr + 12);
          acc[0]=fmaf(w,x0.x,acc[0]);  acc[1]=fmaf(w,x0.y,acc[1]);
          acc[2]=fmaf(w,x0.z,acc[2]);  acc[3]=fmaf(w,x0.w,acc[3]);
          acc[4]=fmaf(w,x1.x,acc[4]);  acc[5]=fmaf(w,x1.y,acc[5]);
          acc[6]=fmaf(w,x1.z,acc[6]);  acc[7]=fmaf(w,x1.w,acc[7]);
          acc[8]=fmaf(w,x2.x,acc[8]);  acc[9]=fmaf(w,x2.y,acc[9]);
          acc[10]=fmaf(w,x2.z,acc[10]); acc[11]=fmaf(w,x2.w,acc[11]);
          acc[12]=fmaf(w,x3.x,acc[12]); acc[13]=fmaf(w,x3.y,acc[13]);
          acc[14]=fmaf(w,x3.z,acc[14]); acc[15]=fmaf(w,x3.w,acc[15]);
        }
      }
      __syncthreads();
      float* part = smem;
      float* cellsL = smem + 8704;            // [16 hp][16 b]
      {
        float* pw = part + (size_t)gr*136u + kh*17;
        #pragma unroll
        for (int b = 0; b < 16; ++b) pw[b] = acc[b];
      }
      __syncthreads();
      if (tid < 256) {
        const int hp2 = tid >> 4, b2 = tid & 15;
        const int bb = bb0 + b2;
        const int j512 = hrg*16 + hp2;
        float gv[4];
        #pragma unroll
        for (int g2 = 0; g2 < 4; ++g2) {
          const float* pr = part + (size_t)(g2*16 + hp2)*136u + b2;
          float s = 0.f;
          #pragma unroll
          for (int k2 = 0; k2 < 8; ++k2) s += pr[k2*17];
          s += (ws + OFF_BB)[g2*512 + j512];
          gv[g2] = s;
        }
        float ig = sigm(gv[0]), fg = sigm(gv[1]);
        float gg = tanhf(gv[2]), og = sigm(gv[3]);
        float* c1 = ws + OFF_C1T + (size_t)j512*128u + bb;
        float cold = *c1;
        float cnew = fg*cold + ig*gg;
        *c1 = cnew;
        float hval = og*tanhf(cnew);
        stv(h1_cur + (size_t)j512*128u + bb, hval);
        cellsL[hp2*16 + b2] = hval;
      }
      __syncthreads();
      if (tid < 256) {                        // transposed, coalesced H1BK store
        const int b2 = tid >> 4, hp2 = tid & 15;
        stv(ws + OFF_H1BK + (size_t)(bb0 + b2)*512u + hrg*16 + hp2,
            cellsL[hp2*16 + b2]);
      }
    }
    gridbar(ws, ++bstep);

    // ========== Phase C : q + pipelined attention (block=(b,tau)) ==========
    {
      const int b = blk >> 1, tau = blk & 1;
      const int tbase = tau*250;
      float* tile = smem;            // [25][520] = 13000
      float* qL   = smem + 13000;    // 512
      float* pL   = smem + 13520;    // 32
      float* sred = smem + 13568;    // [4][512]
      float* h1L  = sred;            // alias (used before sred)

      if (tid < 128) {
        const float* hp = ws + OFF_H1BK + (size_t)b*512u + tid*4;
        float h0v = ldv(hp+0), h1v = ldv(hp+1), h2v = ldv(hp+2), h3v = ldv(hp+3);
        h1L[tid*4+0] = h0v; h1L[tid*4+1] = h1v;
        h1L[tid*4+2] = h2v; h1L[tid*4+3] = h3v;
      }
      __syncthreads();
      // q[d] = sum_e wkT[e][d]*h1[e], 4-way e-split (wkT read-only, L2-resident)
      {
        const int eg = tid >> 7, dqq = (tid & 127)*4;
        const int e0 = eg*128;
        float4 qa = {0.f,0.f,0.f,0.f};
        const float* wkt = ws + OFF_WKT;
        for (int e = 0; e < 128; ++e) {
          float hv = h1L[e0 + e];
          float4 wv4 = *(const float4*)(wkt + (size_t)(e0+e)*512u + dqq);
          qa.x = fmaf(hv, wv4.x, qa.x); qa.y = fmaf(hv, wv4.y, qa.y);
          qa.z = fmaf(hv, wv4.z, qa.z); qa.w = fmaf(hv, wv4.w, qa.w);
        }
        *(float4*)(tile + eg*512 + dqq) = qa;   // tile as scratch
      }
      __syncthreads();
      if (tid < 128) {
        int dqq = tid*4;
        float4 a0 = *(float4*)(tile + dqq);
        float4 a1 = *(float4*)(tile + 512 + dqq);
        float4 a2 = *(float4*)(tile + 1024 + dqq);
        float4 a3 = *(float4*)(tile + 1536 + dqq);
        float4 q4;
        q4.x = a0.x+a1.x+a2.x+a3.x; q4.y = a0.y+a1.y+a2.y+a3.y;
        q4.z = a0.z+a1.z+a2.z+a3.z; q4.w = a0.w+a1.w+a2.w+a3.w;
        *(float4*)(qL + dqq) = q4;
      }
      // prologue: prefetch tile 0 (enc: nontemporal streaming loads)
      float4 rv[7];
      const float* encb = enc + ((size_t)b*TENC + tbase)*EDIM;
      #pragma unroll
      for (int jj = 0; jj < 7; ++jj) {
        int i2 = tid + jj*512;
        if (i2 < 3200) rv[jj] = ld_nt4(encb + (size_t)i2*4u);
      }
      float sa0=0.f, sa1=0.f, sa2=0.f, sa3=0.f;
      float ltot = 0.f;
      const int rr = tid >> 3, cc = tid & 7;
      const int qr = tid >> 7, dqq = (tid & 127)*4;
      const int rs = qr*6 + (qr>0 ? 1 : 0);
      const int rcnt = (qr==0) ? 7 : 6;
      __syncthreads();   // qL ready, tile scratch free
      for (int ti = 0; ti < 10; ++ti) {
        #pragma unroll
        for (int jj = 0; jj < 7; ++jj) {
          int i2 = tid + jj*512;
          if (i2 < 3200) { int r = i2 >> 7, c = i2 & 127; *(float4*)(tile + r*520 + c*4) = rv[jj]; }
        }
        __syncthreads();
        if (ti < 9) {      // prefetch next tile (overlaps compute)
          const float* encn = encb + (size_t)(ti+1)*25u*EDIM;
          #pragma unroll
          for (int jj = 0; jj < 7; ++jj) {
            int i2 = tid + jj*512;
            if (i2 < 3200) rv[jj] = ld_nt4(encn + (size_t)i2*4u);
          }
        }
        if (rr < 25) {
          float a = 0.f;
          const float* tr = tile + rr*520;
          #pragma unroll
          for (int i = 0; i < 16; ++i) {
            int d = i*32 + cc*4;
            float4 tv = *(const float4*)(tr + d);
            float4 qv = *(const float4*)(qL + d);
            a = fmaf(tv.x,qv.x,a); a = fmaf(tv.y,qv.y,a);
            a = fmaf(tv.z,qv.z,a); a = fmaf(tv.w,qv.w,a);
          }
          a += __shfl_xor(a, 1); a += __shfl_xor(a, 2); a += __shfl_xor(a, 4);
          if (cc == 0) {
            float pv = expf(a);
            pL[rr] = pv;
            stv(ws + OFF_P + (size_t)b*512u + tbase + ti*25 + rr, pv);
          }
        }
        __syncthreads();
        if (tid < 32) {
          float pv = (tid < 25) ? pL[tid] : 0.f;
          pv += __shfl_xor(pv, 1); pv += __shfl_xor(pv, 2); pv += __shfl_xor(pv, 4);
          pv += __shfl_xor(pv, 8); pv += __shfl_xor(pv, 16);
          if (tid == 0) ltot += pv;
        }
        {
          const float* tb = tile + dqq;
          for (int r = rs; r < rs + rcnt; ++r) {
            float w = pL[r];
            float4 tv = *(const float4*)(tb + r*520);
            sa0 = fmaf(w, tv.x, sa0); sa1 = fmaf(w, tv.y, sa1);
            sa2 = fmaf(w, tv.z, sa2); sa3 = fmaf(w, tv.w, sa3);
          }
        }
        __syncthreads();
      }
      {
        float4 sv; sv.x = sa0; sv.y = sa1; sv.z = sa2; sv.w = sa3;
        *(float4*)(sred + qr*512 + dqq) = sv;
      }
      __syncthreads();
      if (tid < 128) {
        int d4 = tid*4;
        float4 s0 = *(float4*)(sred + d4);
        float4 s1 = *(float4*)(sred + 512 + d4);
        float4 s2 = *(float4*)(sred + 1024 + d4);
        float4 s3 = *(float4*)(sred + 1536 + d4);
        float* pd = ws + OFF_PS + (size_t)(b*2 + tau)*512u + d4;
        stv(pd+0, s0.x+s1.x+s2.x+s3.x);
        stv(pd+1, s0.y+s1.y+s2.y+s3.y);
        stv(pd+2, s0.z+s1.z+s2.z+s3.z);
        stv(pd+3, s0.w+s1.w+s2.w+s3.w);
      }
      if (tid == 0) stv(ws + OFF_PL + b*2 + tau, ltot);
    }
    gridbar(ws, ++bstep);

    // ========== Phase D : ctx combine + o2c + logits + outputs ==========
    {
      const int bt = blk >> 4, it = blk & 15;
      const int b0 = bt*8, i0 = it*32;
      float* xo   = smem;            // [8][1032]
      float* scsL = smem + 8256;     // 8
      float* hidP = smem + 8264;     // [2][256]
      float* hidL = smem + 8776;     // [8][33]
      if (tid < 8) {
        int bb = b0 + tid;
        float l0 = ldv(ws + OFF_PL + bb*2);
        float l1 = ldv(ws + OFF_PL + bb*2 + 1);
        scsL[tid] = 1.f / (l0 + l1);
      }
      __syncthreads();
      for (int i = tid; i < 1024; i += NTHR) {
        int bl = i >> 7, kq = (i & 127)*4;
        const float* hp = ws + OFF_H1BK + (size_t)(b0+bl)*512u + kq;
        float h0v = ldv(hp+0), h1v = ldv(hp+1), h2v = ldv(hp+2), h3v = ldv(hp+3);
        xo[bl*1032 + kq+0] = h0v; xo[bl*1032 + kq+1] = h1v;
        xo[bl*1032 + kq+2] = h2v; xo[bl*1032 + kq+3] = h3v;
      }
      for (int i = tid; i < 1024; i += NTHR) {
        int bl = i >> 7, dq2 = (i & 127)*4;
        const float* psd = ws + OFF_PS + (size_t)(b0 + bl)*2u*512u;
        float a0 = ldv(psd + dq2+0), a1 = ldv(psd + dq2+1);
        float a2 = ldv(psd + dq2+2), a3 = ldv(psd + dq2+3);
        float b0v = ldv(psd + 512 + dq2+0), b1v = ldv(psd + 512 + dq2+1);
        float b2v = ldv(psd + 512 + dq2+2), b3v = ldv(psd + 512 + dq2+3);
        float sc = scsL[bl];
        xo[bl*1032 + 512 + dq2+0] = (a0+b0v)*sc;
        xo[bl*1032 + 512 + dq2+1] = (a1+b1v)*sc;
        xo[bl*1032 + 512 + dq2+2] = (a2+b2v)*sc;
        xo[bl*1032 + 512 + dq2+3] = (a3+b3v)*sc;
      }
      __syncthreads();
      {
        const int bl = tid & 7, il = (tid >> 3) & 31, kh = tid >> 8;
        float a = 0.f;
        const float4* Gr = (const float4*)(ws + OFF_GM + (size_t)(i0 + il)*1024u + kh*512);
        const float4* xr = (const float4*)(xo + bl*1032 + kh*512);
        for (int k2 = 0; k2 < 128; ++k2) {
          float4 g = Gr[k2], x = xr[k2];
          a = fmaf(g.x,x.x,a); a = fmaf(g.y,x.y,a);
          a = fmaf(g.z,x.z,a); a = fmaf(g.w,x.w,a);
        }
        hidP[(kh << 8) + (tid & 255)] = a;
      }
      __syncthreads();
      if (tid < 256) {
        int bl = tid & 7, il = tid >> 3;
        float h = hidP[tid] + hidP[256 + tid] + (ws + OFF_BG)[i0 + il];
        hidL[bl*33 + il] = fmaxf(h, 0.f);
      }
      if (it == 0) {
        for (int i = tid; i < 1000; i += NTHR) {
          int bl = i / 125, f = i - bl*125;
          int bb = b0 + bl;
          const float* pp = ws + OFF_P + (size_t)bb*512u + f*4;
          float p0v = ldv(pp+0), p1v = ldv(pp+1), p2v = ldv(pp+2), p3v = ldv(pp+3);
          float sc = scsL[bl];
          float4 v; v.x = p0v*sc; v.y = p1v*sc; v.z = p2v*sc; v.w = p3v*sc;
          *(float4*)(attnout + ((size_t)bb*TDEC + t)*TENC + f*4) = v;
        }
        for (int i = tid; i < 4096; i += NTHR) {
          int bl = i & 7, d = i >> 3;
          stv(ws + OFF_ST + (size_t)d*128 + b0 + bl, xo[bl*1032 + 512 + d]);
        }
      }
      __syncthreads();
      if (tid < 248) {
        int bl = tid & 7, v = tid >> 3;
        float s = 0.f;
        const float* er = emb + (size_t)v*512u + i0;
        const float* hrow = hidL + bl*33;
        #pragma unroll
        for (int ii = 0; ii < 32; ++ii) s = fmaf(hrow[ii], er[ii], s);
        float* Lw = ws + OFF_LB + (size_t)p*4096u;
        atomicAdd(&Lw[(b0 + bl)*32 + v], s);   // device-scope atomic (MALL-coherent)
      }
    }
    gridbar(ws, ++bstep);
  } // t loop

  // final logits row (t = 549, parity 1)
  if (hrg == 0 && tid < 496) {
    const float* Lb = ws + OFF_LB + 4096u;
    int bl = tid / 31, v = tid - bl*31;
    int bb = bb0 + bl;
    rawout[((size_t)bb*TDEC + (TDEC-1))*VOC + v] = ldv(Lb + bb*32 + v) + bcp[v];
  }
}

// ---------------- launch ----------------
extern "C" void kernel_launch(void* const* d_in, const int* in_sizes, int n_in,
                              void* d_out, int out_size, void* d_ws, size_t ws_size,
                              hipStream_t stream)
{
  (void)in_sizes; (void)n_in; (void)out_size; (void)ws_size;
  const float* enc   = (const float*)d_in[0];
  const float* emb   = (const float*)d_in[1];
  const float* w_ih0 = (const float*)d_in[2];
  const float* w_hh0 = (const float*)d_in[3];
  const float* b_ih0 = (const float*)d_in[4];
  const float* b_hh0 = (const float*)d_in[5];
  const float* w_ih1 = (const float*)d_in[6];
  const float* w_hh1 = (const float*)d_in[7];
  const float* b_ih1 = (const float*)d_in[8];
  const float* b_hh1 = (const float*)d_in[9];
  const float* wk    = (const float*)d_in[10];
  const float* wvm   = (const float*)d_in[11];
  const float* w_o2c = (const float*)d_in[12];
  const float* b_o2c = (const float*)d_in[13];
  const float* bcp   = (const float*)d_in[14];
  float* ws   = (float*)d_ws;
  float* outp = (float*)d_out;

  initCopy<<<2048, 256, 0, stream>>>(w_hh0, w_ih1, w_hh1, w_o2c,
                                     b_ih0, b_hh0, b_ih1, b_hh1, b_o2c, wk, ws);
  initGemm<<<2048, 256, 0, stream>>>(w_ih0, w_o2c, wvm, emb, ws);
  speller_main<<<NBLK, NTHR, 0, stream>>>(enc, emb, wk, bcp, ws, outp);
}

// Round 4
// 74945.026 us; speedup vs baseline: 4.0504x; 1.0487x over previous
//
#include <hip/hip_runtime.h>
#include <math.h>

#define BATCH 128
#define TDEC  550
#define TENC  500
#define EDIM  512
#define VOC   31
#define NBLK  256
#define NTHR  512

// ---------------- workspace layout (float offsets) ----------------
// WA/WB are TRANSPOSED (k-major): WAT[k][j] with k in [0,1024), j in [0,2048)
#define OFF_WA   0u                          // WAT [1024][2048]: k<512 = M (s-part), k>=512 = w_hh0
#define OFF_WB   (OFF_WA + 2097152u)         // WBT [1024][2048]: k<512 = w_ih1,      k>=512 = w_hh1
#define OFF_GM   (OFF_WB + 2097152u)         // [512][1024]  cols 0..511 = w_o2c[:, :512], 512.. = M2
#define OFF_E2G  (OFF_GM + 524288u)          // [31][2048]
#define OFF_BA   (OFF_E2G + 63488u)          // [2048]
#define OFF_BB   (OFF_BA + 2048u)            // [2048]
#define OFF_BG   (OFF_BB + 2048u)            // [512]
#define OFF_ST   (OFF_BG + 512u)             // s~ [512][128]
#define OFF_H0T0 (OFF_ST   + 65536u)
#define OFF_H0T1 (OFF_H0T0 + 65536u)
#define OFF_H1T0 (OFF_H0T1 + 65536u)
#define OFF_H1T1 (OFF_H1T0 + 65536u)
#define OFF_C0T  (OFF_H1T1 + 65536u)
#define OFF_C1T  (OFF_C0T  + 65536u)
#define OFF_P    (OFF_C1T  + 65536u)         // exp(e) [128][512] (500 used)
#define OFF_PL   (OFF_P    + 65536u)         // l partials [128][2]
#define OFF_PS   (OFF_PL   + 256u)           // s partials [128][2][512]
#define OFF_LB   (OFF_PS   + 131072u)        // logits dbl-buf [2][128][32]
#define OFF_BAR  (OFF_LB   + 8192u)          // barrier: 8 groups x 1024 u32
#define OFF_WKT  (OFF_BAR  + 8192u)          // wkT [512 e][512 d]
#define OFF_H1BK (OFF_WKT  + 262144u)        // h1 in [b][k] layout [128][512]

typedef float f32x4_t __attribute__((ext_vector_type(4)));

// ---------------- device-coherent accessors (compiler-visible) ----------------
// Relaxed agent-scope atomics -> device-scope (sc1) dword ops at the MALL
// coherence point.  Only small mutable cross-block state uses these.
__device__ __forceinline__ float ldv(const float* p) {
  return __hip_atomic_load((const float*)p, __ATOMIC_RELAXED, __HIP_MEMORY_SCOPE_AGENT);
}
__device__ __forceinline__ void stv(float* p, float v) {
  __hip_atomic_store(p, v, __ATOMIC_RELAXED, __HIP_MEMORY_SCOPE_AGENT);
}
// nontemporal float4 load: streams without polluting L2 (protects resident weights)
__device__ __forceinline__ float4 ld_nt4(const float* p) {
  f32x4_t v = __builtin_nontemporal_load((const f32x4_t*)p);
  float4 r; r.x = v.x; r.y = v.y; r.z = v.z; r.w = v.w; return r;
}

// ---------------- init kernel 1: copies / biases / zeros / wkT ----------------
__global__ void initCopy(const float* __restrict__ w_hh0, const float* __restrict__ w_ih1,
                         const float* __restrict__ w_hh1, const float* __restrict__ w_o2c,
                         const float* __restrict__ b_ih0, const float* __restrict__ b_hh0,
                         const float* __restrict__ b_ih1, const float* __restrict__ b_hh1,
                         const float* __restrict__ b_o2c, const float* __restrict__ wk,
                         float* __restrict__ ws)
{
  const unsigned n0 = 2048u*512u;      // WAT upper (w_hh0), transposed
  const unsigned n1 = 2048u*512u;      // WBT lower (w_ih1), transposed
  const unsigned n2 = 2048u*512u;      // WBT upper (w_hh1), transposed
  const unsigned n3 = 512u*512u;       // GM left
  const unsigned nz = 7u*65536u;       // ST,H0T0,H0T1,H1T0,H1T1,C0T,C1T
  const unsigned nw = 262144u;         // wkT
  const unsigned NT = n0+n1+n2+n3 + 2048u+2048u+512u + nz + 8192u + 8192u + nw;
  for (unsigned i = blockIdx.x*blockDim.x + threadIdx.x; i < NT; i += gridDim.x*blockDim.x) {
    unsigned j = i;
    if (j < n0) { unsigned r = j & 2047u, k = j >> 11;
      ws[OFF_WA + (512u + k)*2048u + r] = w_hh0[(size_t)r*512u + k]; continue; }
    j -= n0;
    if (j < n1) { unsigned r = j & 2047u, k = j >> 11;
      ws[OFF_WB + k*2048u + r] = w_ih1[(size_t)r*512u + k]; continue; }
    j -= n1;
    if (j < n2) { unsigned r = j & 2047u, k = j >> 11;
      ws[OFF_WB + (512u + k)*2048u + r] = w_hh1[(size_t)r*512u + k]; continue; }
    j -= n2;
    if (j < n3) { unsigned r = j>>9, k = j&511u;
      ws[OFF_GM + r*1024u + k] = w_o2c[r*1024u + k]; continue; }
    j -= n3;
    if (j < 2048u) { ws[OFF_BA + j] = b_ih0[j] + b_hh0[j]; continue; }
    j -= 2048u;
    if (j < 2048u) { ws[OFF_BB + j] = b_ih1[j] + b_hh1[j]; continue; }
    j -= 2048u;
    if (j < 512u)  { ws[OFF_BG + j] = b_o2c[j]; continue; }
    j -= 512u;
    if (j < nz)    { ws[OFF_ST + j] = 0.f; continue; }
    j -= nz;
    if (j < 8192u) {
      unsigned buf = j>>12, v = j & 31u;
      ws[OFF_LB + j] = (buf==1u && v==0u) ? 1e9f : 0.f;   // argmax -> SOS(=0) at t=0
      continue; }
    j -= 8192u;
    if (j < 8192u) { ((unsigned*)(ws + OFF_BAR))[j] = 0u; continue; }
    j -= 8192u;
    { unsigned e = j>>9, d = j&511u;
      ws[OFF_WKT + j] = wk[d*512u + e]; }
  }
}

// ---------------- init kernel 2: folded weight GEMMs ----------------
__global__ void initGemm(const float* __restrict__ w_ih0, const float* __restrict__ w_o2c,
                         const float* __restrict__ wvm, const float* __restrict__ emb,
                         float* __restrict__ ws)
{
  const unsigned n0 = 2048u*512u;   // M  -> WAT lower half (transposed)
  const unsigned n1 = 512u*512u;    // M2 -> GM right
  const unsigned n2 = 31u*2048u;    // E2G
  const unsigned NT = n0+n1+n2;
  for (unsigned i = blockIdx.x*blockDim.x + threadIdx.x; i < NT; i += gridDim.x*blockDim.x) {
    if (i < n0) {
      unsigned r = i & 2047u, d = i >> 11;
      const float* a = w_ih0 + (size_t)r*1024u + 512u;
      const float* b = wvm + (size_t)d*512u;
      float s = 0.f;
      for (int k = 0; k < 512; ++k) s = fmaf(a[k], b[k], s);
      ws[OFF_WA + d*2048u + r] = s;
    } else if (i < n0+n1) {
      unsigned j = i - n0; unsigned r = j>>9, d = j&511u;
      const float* a = w_o2c + (size_t)r*1024u + 512u;
      const float* b = wvm + (size_t)d*512u;
      float s = 0.f;
      for (int k = 0; k < 512; ++k) s = fmaf(a[k], b[k], s);
      ws[OFF_GM + r*1024u + 512u + d] = s;
    } else {
      unsigned j = i - n0 - n1; unsigned v = j>>11, g = j&2047u;
      const float* a = emb + (size_t)v*512u;
      const float* b = w_ih0 + (size_t)g*1024u;
      float s = 0.f;
      for (int k = 0; k < 512; ++k) s = fmaf(a[k], b[k], s);
      ws[OFF_E2G + v*2048u + g] = s;
    }
  }
}

// ---------------- fence-free GROUP barrier (32 blocks sharing one batch-group)
// The whole computation is batch-local: groups of 32 blocks (same bg) share
// NO mutable state with other groups.  Group barriers cut the fan-in 256->32,
// remove cross-group tail coupling, and let groups drift so memory-heavy
// phase C of one group overlaps compute of another.
__device__ __forceinline__ void groupbar(float* ws, int bg, int r5, unsigned tgt)
{
  unsigned* base = (unsigned*)(ws + OFF_BAR) + bg*1024;
  asm volatile("s_waitcnt vmcnt(0)" ::: "memory");   // own sc1 stores at coherence point
  __syncthreads();
  if (r5 == 0) {
    const int tid = threadIdx.x;
    if (tid > 0 && tid < 32) {
      unsigned* f = base + tid*16;
      while (__hip_atomic_load(f, __ATOMIC_RELAXED, __HIP_MEMORY_SCOPE_AGENT) < tgt)
        __builtin_amdgcn_s_sleep(2);
    }
    __syncthreads();
    if (tid == 0)
      __hip_atomic_store(base + 512, tgt, __ATOMIC_RELAXED, __HIP_MEMORY_SCOPE_AGENT);
    __syncthreads();
  } else {
    if (threadIdx.x == 0) {
      __hip_atomic_store(base + r5*16, tgt, __ATOMIC_RELAXED, __HIP_MEMORY_SCOPE_AGENT);
      while (__hip_atomic_load(base + 512, __ATOMIC_RELAXED, __HIP_MEMORY_SCOPE_AGENT) < tgt)
        __builtin_amdgcn_s_sleep(2);
    }
    __syncthreads();
  }
}

__device__ __forceinline__ float sigm(float x) { return 1.f/(1.f + expf(-x)); }

// ---------------- main persistent kernel ----------------
__launch_bounds__(NTHR)
__global__ void speller_main(const float* __restrict__ enc, const float* __restrict__ emb,
                             const float* __restrict__ wk,  const float* __restrict__ bcp,
                             float* __restrict__ ws, float* __restrict__ out)
{
  __shared__ __align__(16) float smem[15616];
  __shared__ unsigned long long amx[16];
  const int tid = threadIdx.x;
  const int blk = blockIdx.x;
  unsigned bstep = 0;

  float* rawout  = out;                                   // [128][550][31]
  float* attnout = out + (size_t)BATCH*TDEC*VOC;          // [128][550][500]

  // LSTM tiling: 32 hidden-rowgroups x 8 batchgroups, XCD-affine rowgroups
  const int r5  = blk & 31;
  const int hrg = (r5 & 7)*4 + (r5 >> 3);   // blk%8 == hrg>>2 -> XCD-contiguous j-cols
  const int bg  = blk >> 5;
  const int bb0 = bg * 16;

  for (int t = 0; t < TDEC; ++t) {
    const int p = t & 1;
    float*       h0_cur  = ws + (p ? OFF_H0T1 : OFF_H0T0);
    const float* h0_prev = ws + (p ? OFF_H0T0 : OFF_H0T1);
    float*       h1_cur  = ws + (p ? OFF_H1T1 : OFF_H1T0);
    const float* h1_prev = ws + (p ? OFF_H1T0 : OFF_H1T1);

    // ========== Phase A : argmax feedback + LSTM0 ==========
    {
      const float* Lb = ws + OFF_LB + (size_t)(p^1)*4096u;
      if (tid < 16) amx[tid] = 0ull;
      __syncthreads();
      // roles: rawout trickle (hrg==0), LB[p] zeroing (hrg==1)
      if (hrg == 0 && t > 0 && tid < 496) {
        int bl = tid / 31, v = tid - bl*31;
        int bb = bb0 + bl;
        rawout[((size_t)bb*TDEC + (t-1))*VOC + v] = ldv(Lb + bb*32 + v) + bcp[v];
      }
      if (hrg == 1) {
        float* Lz = ws + OFF_LB + (size_t)p*4096u + (size_t)bb0*32u;
        if (tid < 512) stv(Lz + tid, 0.f);
      }
      // parallel argmax for this block's 16 batches (exact first-max semantics)
      if (tid < 496) {
        int bl = tid / 31, v = tid - bl*31;
        float f = ldv(Lb + (size_t)(bb0 + bl)*32u + v) + bcp[v];
        unsigned ub = __float_as_uint(f);
        ub = (ub & 0x80000000u) ? ~ub : (ub | 0x80000000u);
        unsigned long long key = ((unsigned long long)ub << 32) | (unsigned)(31 - v);
        atomicMax(&amx[bl], key);
      }
      // LSTM0 gates: thread (gr,kh): gr=gate-row (4 gates x 16 hidden), kh=k-split
      const int gr = tid & 63, kh = tid >> 6;
      const int gi = gr >> 4, hp = gr & 15;
      const int j  = gi*512 + hrg*16 + hp;
      const float* wcol = ws + OFF_WA + j;
      float acc[16];
      #pragma unroll
      for (int b = 0; b < 16; ++b) acc[b] = 0.f;
      float* xs = smem;                       // [512][16] staged x-slice
      #pragma unroll 1
      for (int pass = 0; pass < 2; ++pass) {
        const float* src = pass ? h0_prev : (ws + OFF_ST);
        __syncthreads();                      // previous contents consumed
        float tmp[16];
        #pragma unroll
        for (int u = 0; u < 16; ++u) {
          int i = tid + u*512;
          tmp[u] = ldv(src + (size_t)(i >> 4)*128u + bb0 + (i & 15));
        }
        #pragma unroll
        for (int u = 0; u < 16; ++u) xs[tid + u*512] = tmp[u];
        __syncthreads();
        const int kb = kh * 64;
        #pragma unroll 8
        for (int kk = 0; kk < 64; ++kk) {
          float w = wcol[(size_t)(pass*512 + kb + kk)*2048u];
          const float* xr = xs + (size_t)(kb + kk)*16u;
          float4 x0 = *(const float4*)(xr);
          float4 x1 = *(const float4*)(xr + 4);
          float4 x2 = *(const float4*)(xr + 8);
          float4 x3 = *(const float4*)(xr + 12);
          acc[0]=fmaf(w,x0.x,acc[0]);  acc[1]=fmaf(w,x0.y,acc[1]);
          acc[2]=fmaf(w,x0.z,acc[2]);  acc[3]=fmaf(w,x0.w,acc[3]);
          acc[4]=fmaf(w,x1.x,acc[4]);  acc[5]=fmaf(w,x1.y,acc[5]);
          acc[6]=fmaf(w,x1.z,acc[6]);  acc[7]=fmaf(w,x1.w,acc[7]);
          acc[8]=fmaf(w,x2.x,acc[8]);  acc[9]=fmaf(w,x2.y,acc[9]);
          acc[10]=fmaf(w,x2.z,acc[10]); acc[11]=fmaf(w,x2.w,acc[11]);
          acc[12]=fmaf(w,x3.x,acc[12]); acc[13]=fmaf(w,x3.y,acc[13]);
          acc[14]=fmaf(w,x3.z,acc[14]); acc[15]=fmaf(w,x3.w,acc[15]);
        }
      }
      __syncthreads();
      float* part = smem;                     // overlays xs: [64 gr][8 kh][17 pad]
      {
        float* pw = part + (size_t)gr*136u + kh*17;
        #pragma unroll
        for (int b = 0; b < 16; ++b) pw[b] = acc[b];
      }
      __syncthreads();
      if (tid < 256) {
        const int hp2 = tid >> 4, b2 = tid & 15;
        const int bb = bb0 + b2;
        const int j512 = hrg*16 + hp2;
        const int sy = 31 - (int)(amx[b2] & 31ull);
        float gv[4];
        #pragma unroll
        for (int g2 = 0; g2 < 4; ++g2) {
          const float* pr = part + (size_t)(g2*16 + hp2)*136u + b2;
          float s = 0.f;
          #pragma unroll
          for (int k2 = 0; k2 < 8; ++k2) s += pr[k2*17];
          s += (ws + OFF_E2G)[(size_t)sy*2048u + g2*512 + j512];
          s += (ws + OFF_BA)[g2*512 + j512];
          gv[g2] = s;
        }
        float ig = sigm(gv[0]), fg = sigm(gv[1]);
        float gg = tanhf(gv[2]), og = sigm(gv[3]);
        float* c0 = ws + OFF_C0T + (size_t)j512*128u + bb;   // block-private: cached
        float cold = *c0;
        float cnew = fg*cold + ig*gg;
        *c0 = cnew;
        stv(h0_cur + (size_t)j512*128u + bb, og*tanhf(cnew));
      }
    }
    groupbar(ws, bg, r5, ++bstep);

    // ========== Phase B : LSTM1 (+ H1BK transposed copy) ==========
    {
      const int gr = tid & 63, kh = tid >> 6;
      const int gi = gr >> 4, hp = gr & 15;
      const int j  = gi*512 + hrg*16 + hp;
      const float* wcol = ws + OFF_WB + j;
      float acc[16];
      #pragma unroll
      for (int b = 0; b < 16; ++b) acc[b] = 0.f;
      float* xs = smem;
      #pragma unroll 1
      for (int pass = 0; pass < 2; ++pass) {
        const float* src = pass ? h1_prev : h0_cur;
        __syncthreads();
        float tmp[16];
        #pragma unroll
        for (int u = 0; u < 16; ++u) {
          int i = tid + u*512;
          tmp[u] = ldv(src + (size_t)(i >> 4)*128u + bb0 + (i & 15));
        }
        #pragma unroll
        for (int u = 0; u < 16; ++u) xs[tid + u*512] = tmp[u];
        __syncthreads();
        const int kb = kh * 64;
        #pragma unroll 8
        for (int kk = 0; kk < 64; ++kk) {
          float w = wcol[(size_t)(pass*512 + kb + kk)*2048u];
          const float* xr = xs + (size_t)(kb + kk)*16u;
          float4 x0 = *(const float4*)(xr);
          float4 x1 = *(const float4*)(xr + 4);
          float4 x2 = *(const float4*)(xr + 8);
          float4 x3 = *(const float4*)(xr + 12);
          acc[0]=fmaf(w,x0.x,acc[0]);  acc[1]=fmaf(w,x0.y,acc[1]);
          acc[2]=fmaf(w,x0.z,acc[2]);  acc[3]=fmaf(w,x0.w,acc[3]);
          acc[4]=fmaf(w,x1.x,acc[4]);  acc[5]=fmaf(w,x1.y,acc[5]);
          acc[6]=fmaf(w,x1.z,acc[6]);  acc[7]=fmaf(w,x1.w,acc[7]);
          acc[8]=fmaf(w,x2.x,acc[8]);  acc[9]=fmaf(w,x2.y,acc[9]);
          acc[10]=fmaf(w,x2.z,acc[10]); acc[11]=fmaf(w,x2.w,acc[11]);
          acc[12]=fmaf(w,x3.x,acc[12]); acc[13]=fmaf(w,x3.y,acc[13]);
          acc[14]=fmaf(w,x3.z,acc[14]); acc[15]=fmaf(w,x3.w,acc[15]);
        }
      }
      __syncthreads();
      float* part = smem;
      float* cellsL = smem + 8704;            // [16 hp][16 b]
      {
        float* pw = part + (size_t)gr*136u + kh*17;
        #pragma unroll
        for (int b = 0; b < 16; ++b) pw[b] = acc[b];
      }
      __syncthreads();
      if (tid < 256) {
        const int hp2 = tid >> 4, b2 = tid & 15;
        const int bb = bb0 + b2;
        const int j512 = hrg*16 + hp2;
        float gv[4];
        #pragma unroll
        for (int g2 = 0; g2 < 4; ++g2) {
          const float* pr = part + (size_t)(g2*16 + hp2)*136u + b2;
          float s = 0.f;
          #pragma unroll
          for (int k2 = 0; k2 < 8; ++k2) s += pr[k2*17];
          s += (ws + OFF_BB)[g2*512 + j512];
          gv[g2] = s;
        }
        float ig = sigm(gv[0]), fg = sigm(gv[1]);
        float gg = tanhf(gv[2]), og = sigm(gv[3]);
        float* c1 = ws + OFF_C1T + (size_t)j512*128u + bb;
        float cold = *c1;
        float cnew = fg*cold + ig*gg;
        *c1 = cnew;
        float hval = og*tanhf(cnew);
        stv(h1_cur + (size_t)j512*128u + bb, hval);
        cellsL[hp2*16 + b2] = hval;
      }
      __syncthreads();
      if (tid < 256) {                        // transposed, coalesced H1BK store
        const int b2 = tid >> 4, hp2 = tid & 15;
        stv(ws + OFF_H1BK + (size_t)(bb0 + b2)*512u + hrg*16 + hp2,
            cellsL[hp2*16 + b2]);
      }
    }
    groupbar(ws, bg, r5, ++bstep);

    // ========== Phase C : q + pipelined attention (group-local: b in this bg) ==========
    {
      const int b = bb0 + (r5 >> 1), tau = r5 & 1;
      const int tbase = tau*250;
      float* tile = smem;            // [25][520] = 13000
      float* qL   = smem + 13000;    // 512
      float* pL   = smem + 13520;    // 32
      float* sred = smem + 13568;    // [4][512]
      float* h1L  = sred;            // alias (used before sred)

      if (tid < 128) {
        const float* hp = ws + OFF_H1BK + (size_t)b*512u + tid*4;
        float h0v = ldv(hp+0), h1v = ldv(hp+1), h2v = ldv(hp+2), h3v = ldv(hp+3);
        h1L[tid*4+0] = h0v; h1L[tid*4+1] = h1v;
        h1L[tid*4+2] = h2v; h1L[tid*4+3] = h3v;
      }
      __syncthreads();
      // q[d] = sum_e wkT[e][d]*h1[e], 4-way e-split (wkT read-only, L2-resident)
      {
        const int eg = tid >> 7, dqq = (tid & 127)*4;
        const int e0 = eg*128;
        float4 qa = {0.f,0.f,0.f,0.f};
        const float* wkt = ws + OFF_WKT;
        for (int e = 0; e < 128; ++e) {
          float hv = h1L[e0 + e];
          float4 wv4 = *(const float4*)(wkt + (size_t)(e0+e)*512u + dqq);
          qa.x = fmaf(hv, wv4.x, qa.x); qa.y = fmaf(hv, wv4.y, qa.y);
          qa.z = fmaf(hv, wv4.z, qa.z); qa.w = fmaf(hv, wv4.w, qa.w);
        }
        *(float4*)(tile + eg*512 + dqq) = qa;   // tile as scratch
      }
      __syncthreads();
      if (tid < 128) {
        int dqq = tid*4;
        float4 a0 = *(float4*)(tile + dqq);
        float4 a1 = *(float4*)(tile + 512 + dqq);
        float4 a2 = *(float4*)(tile + 1024 + dqq);
        float4 a3 = *(float4*)(tile + 1536 + dqq);
        float4 q4;
        q4.x = a0.x+a1.x+a2.x+a3.x; q4.y = a0.y+a1.y+a2.y+a3.y;
        q4.z = a0.z+a1.z+a2.z+a3.z; q4.w = a0.w+a1.w+a2.w+a3.w;
        *(float4*)(qL + dqq) = q4;
      }
      // prologue: prefetch tile 0 (enc: nontemporal streaming loads)
      float4 rv[7];
      const float* encb = enc + ((size_t)b*TENC + tbase)*EDIM;
      #pragma unroll
      for (int jj = 0; jj < 7; ++jj) {
        int i2 = tid + jj*512;
        if (i2 < 3200) rv[jj] = ld_nt4(encb + (size_t)i2*4u);
      }
      float sa0=0.f, sa1=0.f, sa2=0.f, sa3=0.f;
      float ltot = 0.f;
      const int rr = tid >> 3, cc = tid & 7;
      const int qr = tid >> 7, dqq = (tid & 127)*4;
      const int rs = qr*6 + (qr>0 ? 1 : 0);
      const int rcnt = (qr==0) ? 7 : 6;
      __syncthreads();   // qL ready, tile scratch free
      for (int ti = 0; ti < 10; ++ti) {
        #pragma unroll
        for (int jj = 0; jj < 7; ++jj) {
          int i2 = tid + jj*512;
          if (i2 < 3200) { int r = i2 >> 7, c = i2 & 127; *(float4*)(tile + r*520 + c*4) = rv[jj]; }
        }
        __syncthreads();
        if (ti < 9) {      // prefetch next tile (overlaps compute)
          const float* encn = encb + (size_t)(ti+1)*25u*EDIM;
          #pragma unroll
          for (int jj = 0; jj < 7; ++jj) {
            int i2 = tid + jj*512;
            if (i2 < 3200) rv[jj] = ld_nt4(encn + (size_t)i2*4u);
          }
        }
        if (rr < 25) {
          float a = 0.f;
          const float* tr = tile + rr*520;
          #pragma unroll
          for (int i = 0; i < 16; ++i) {
            int d = i*32 + cc*4;
            float4 tv = *(const float4*)(tr + d);
            float4 qv = *(const float4*)(qL + d);
            a = fmaf(tv.x,qv.x,a); a = fmaf(tv.y,qv.y,a);
            a = fmaf(tv.z,qv.z,a); a = fmaf(tv.w,qv.w,a);
          }
          a += __shfl_xor(a, 1); a += __shfl_xor(a, 2); a += __shfl_xor(a, 4);
          if (cc == 0) {
            float pv = expf(a);
            pL[rr] = pv;
            stv(ws + OFF_P + (size_t)b*512u + tbase + ti*25 + rr, pv);
          }
        }
        __syncthreads();
        if (tid < 32) {
          float pv = (tid < 25) ? pL[tid] : 0.f;
          pv += __shfl_xor(pv, 1); pv += __shfl_xor(pv, 2); pv += __shfl_xor(pv, 4);
          pv += __shfl_xor(pv, 8); pv += __shfl_xor(pv, 16);
          if (tid == 0) ltot += pv;
        }
        {
          const float* tb = tile + dqq;
          for (int r = rs; r < rs + rcnt; ++r) {
            float w = pL[r];
            float4 tv = *(const float4*)(tb + r*520);
            sa0 = fmaf(w, tv.x, sa0); sa1 = fmaf(w, tv.y, sa1);
            sa2 = fmaf(w, tv.z, sa2); sa3 = fmaf(w, tv.w, sa3);
          }
        }
        __syncthreads();
      }
      {
        float4 sv; sv.x = sa0; sv.y = sa1; sv.z = sa2; sv.w = sa3;
        *(float4*)(sred + qr*512 + dqq) = sv;
      }
      __syncthreads();
      if (tid < 128) {
        int d4 = tid*4;
        float4 s0 = *(float4*)(sred + d4);
        float4 s1 = *(float4*)(sred + 512 + d4);
        float4 s2 = *(float4*)(sred + 1024 + d4);
        float4 s3 = *(float4*)(sred + 1536 + d4);
        float* pd = ws + OFF_PS + (size_t)(b*2 + tau)*512u + d4;
        stv(pd+0, s0.x+s1.x+s2.x+s3.x);
        stv(pd+1, s0.y+s1.y+s2.y+s3.y);
        stv(pd+2, s0.z+s1.z+s2.z+s3.z);
        stv(pd+3, s0.w+s1.w+s2.w+s3.w);
      }
      if (tid == 0) stv(ws + OFF_PL + b*2 + tau, ltot);
    }
    groupbar(ws, bg, r5, ++bstep);

    // ========== Phase D : ctx combine + o2c + logits + outputs (group-local) ==========
    {
      const int bh = r5 >> 4, it = r5 & 15;
      const int b0 = bb0 + bh*8, i0 = it*32;
      float* xo   = smem;            // [8][1032]
      float* scsL = smem + 8256;     // 8
      float* hidP = smem + 8264;     // [2][256]
      float* hidL = smem + 8776;     // [8][33]
      if (tid < 8) {
        int bb = b0 + tid;
        float l0 = ldv(ws + OFF_PL + bb*2);
        float l1 = ldv(ws + OFF_PL + bb*2 + 1);
        scsL[tid] = 1.f / (l0 + l1);
      }
      __syncthreads();
      for (int i = tid; i < 1024; i += NTHR) {
        int bl = i >> 7, kq = (i & 127)*4;
        const float* hp = ws + OFF_H1BK + (size_t)(b0+bl)*512u + kq;
        float h0v = ldv(hp+0), h1v = ldv(hp+1), h2v = ldv(hp+2), h3v = ldv(hp+3);
        xo[bl*1032 + kq+0] = h0v; xo[bl*1032 + kq+1] = h1v;
        xo[bl*1032 + kq+2] = h2v; xo[bl*1032 + kq+3] = h3v;
      }
      for (int i = tid; i < 1024; i += NTHR) {
        int bl = i >> 7, dq2 = (i & 127)*4;
        const float* psd = ws + OFF_PS + (size_t)(b0 + bl)*2u*512u;
        float a0 = ldv(psd + dq2+0), a1 = ldv(psd + dq2+1);
        float a2 = ldv(psd + dq2+2), a3 = ldv(psd + dq2+3);
        float b0v = ldv(psd + 512 + dq2+0), b1v = ldv(psd + 512 + dq2+1);
        float b2v = ldv(psd + 512 + dq2+2), b3v = ldv(psd + 512 + dq2+3);
        float sc = scsL[bl];
        xo[bl*1032 + 512 + dq2+0] = (a0+b0v)*sc;
        xo[bl*1032 + 512 + dq2+1] = (a1+b1v)*sc;
        xo[bl*1032 + 512 + dq2+2] = (a2+b2v)*sc;
        xo[bl*1032 + 512 + dq2+3] = (a3+b3v)*sc;
      }
      __syncthreads();
      {
        const int bl = tid & 7, il = (tid >> 3) & 31, kh = tid >> 8;
        float a = 0.f;
        const float4* Gr = (const float4*)(ws + OFF_GM + (size_t)(i0 + il)*1024u + kh*512);
        const float4* xr = (const float4*)(xo + bl*1032 + kh*512);
        for (int k2 = 0; k2 < 128; ++k2) {
          float4 g = Gr[k2], x = xr[k2];
          a = fmaf(g.x,x.x,a); a = fmaf(g.y,x.y,a);
          a = fmaf(g.z,x.z,a); a = fmaf(g.w,x.w,a);
        }
        hidP[(kh << 8) + (tid & 255)] = a;
      }
      __syncthreads();
      if (tid < 256) {
        int bl = tid & 7, il = tid >> 3;
        float h = hidP[tid] + hidP[256 + tid] + (ws + OFF_BG)[i0 + il];
        hidL[bl*33 + il] = fmaxf(h, 0.f);
      }
      if (it == 0) {
        for (int i = tid; i < 1000; i += NTHR) {
          int bl = i / 125, f = i - bl*125;
          int bb = b0 + bl;
          const float* pp = ws + OFF_P + (size_t)bb*512u + f*4;
          float p0v = ldv(pp+0), p1v = ldv(pp+1), p2v = ldv(pp+2), p3v = ldv(pp+3);
          float sc = scsL[bl];
          float4 v; v.x = p0v*sc; v.y = p1v*sc; v.z = p2v*sc; v.w = p3v*sc;
          *(float4*)(attnout + ((size_t)bb*TDEC + t)*TENC + f*4) = v;
        }
        for (int i = tid; i < 4096; i += NTHR) {
          int bl = i & 7, d = i >> 3;
          stv(ws + OFF_ST + (size_t)d*128 + b0 + bl, xo[bl*1032 + 512 + d]);
        }
      }
      __syncthreads();
      if (tid < 248) {
        int bl = tid & 7, v = tid >> 3;
        float s = 0.f;
        const float* er = emb + (size_t)v*512u + i0;
        const float* hrow = hidL + bl*33;
        #pragma unroll
        for (int ii = 0; ii < 32; ++ii) s = fmaf(hrow[ii], er[ii], s);
        float* Lw = ws + OFF_LB + (size_t)p*4096u;
        atomicAdd(&Lw[(b0 + bl)*32 + v], s);   // device-scope atomic (MALL-coherent)
      }
    }
    groupbar(ws, bg, r5, ++bstep);
  } // t loop

  // final logits row (t = 549, parity 1)
  if (hrg == 0 && tid < 496) {
    const float* Lb = ws + OFF_LB + 4096u;
    int bl = tid / 31, v = tid - bl*31;
    int bb = bb0 + bl;
    rawout[((size_t)bb*TDEC + (TDEC-1))*VOC + v] = ldv(Lb + bb*32 + v) + bcp[v];
  }
}

// ---------------- launch ----------------
extern "C" void kernel_launch(void* const* d_in, const int* in_sizes, int n_in,
                              void* d_out, int out_size, void* d_ws, size_t ws_size,
                              hipStream_t stream)
{
  (void)in_sizes; (void)n_in; (void)out_size; (void)ws_size;
  const float* enc   = (const float*)d_in[0];
  const float* emb   = (const float*)d_in[1];
  const float* w_ih0 = (const float*)d_in[2];
  const float* w_hh0 = (const float*)d_in[3];
  const float* b_ih0 = (const float*)d_in[4];
  const float* b_hh0 = (const float*)d_in[5];
  const float* w_ih1 = (const float*)d_in[6];
  const float* w_hh1 = (const float*)d_in[7];
  const float* b_ih1 = (const float*)d_in[8];
  const float* b_hh1 = (const float*)d_in[9];
  const float* wk    = (const float*)d_in[10];
  const float* wvm   = (const float*)d_in[11];
  const float* w_o2c = (const float*)d_in[12];
  const float* b_o2c = (const float*)d_in[13];
  const float* bcp   = (const float*)d_in[14];
  float* ws   = (float*)d_ws;
  float* outp = (float*)d_out;

  initCopy<<<2048, 256, 0, stream>>>(w_hh0, w_ih1, w_hh1, w_o2c,
                                     b_ih0, b_hh0, b_ih1, b_hh1, b_o2c, wk, ws);
  initGemm<<<2048, 256, 0, stream>>>(w_ih0, w_o2c, wvm, emb, ws);
  speller_main<<<NBLK, NTHR, 0, stream>>>(enc, emb, wk, bcp, ws, outp);
}